// Round 1
// baseline (414.691 us; speedup 1.0000x reference)
//
#include <hip/hip_runtime.h>

#define N_NODES 100000
#define D_INF   128
#define D_HID   256
#define K_CL    16
#define N_EDGES 3200000

// ---------------------------------------------------------------------------
// Fused MLP: h = relu(x@W1 + b1); C = softmax(h@W2 + b2)
// Block = 256 threads, tile = 64 nodes.
// Thread (tr = tid>>4, tc = tid&15) computes nodes tr*4..tr*4+3 for
// hidden cols j0 = tc*16 .. tc*16+15 (register tile 4x16),
// then GEMM2 partials reduced across the 16 tc-lanes via shfl_xor.
// ---------------------------------------------------------------------------
__global__ __launch_bounds__(256, 2) void mlp_kernel(
    const float* __restrict__ x, const float* __restrict__ W1,
    const float* __restrict__ b1, const float* __restrict__ W2,
    const float* __restrict__ b2, float* __restrict__ C)
{
    // padded stride 132: distinct tr addresses land on 2 banks -> free 2-way
    __shared__ float Xs[64 * 132];

    const int tid = threadIdx.x;
    const int m0  = blockIdx.x * 64;

    // ---- stage x tile (64 rows x 128 cols), zero-pad invalid rows ----
    #pragma unroll
    for (int i = tid; i < 64 * 32; i += 256) {        // float4 chunks
        const int row = i >> 5, c4 = i & 31;
        float4 v = make_float4(0.f, 0.f, 0.f, 0.f);
        if (m0 + row < N_NODES)
            v = *(const float4*)(x + (size_t)(m0 + row) * D_INF + c4 * 4);
        *(float4*)&Xs[row * 132 + c4 * 4] = v;
    }
    __syncthreads();

    const int tc = tid & 15;   // hidden-col group
    const int tr = tid >> 4;   // node group
    const int j0 = tc * 16;

    // ---- GEMM1: acc[mi][q] = b1[j0+q] + sum_k x[m][k]*W1[k][j0+q] ----
    float acc[4][16];
    #pragma unroll
    for (int mi = 0; mi < 4; mi++)
        #pragma unroll
        for (int q = 0; q < 16; q++)
            acc[mi][q] = b1[j0 + q];

    for (int k0 = 0; k0 < D_INF; k0 += 4) {
        float4 xv[4];
        #pragma unroll
        for (int mi = 0; mi < 4; mi++)
            xv[mi] = *(const float4*)&Xs[(tr * 4 + mi) * 132 + k0];
        float4 wv[4][4];
        #pragma unroll
        for (int kk = 0; kk < 4; kk++)
            #pragma unroll
            for (int q = 0; q < 4; q++)
                wv[kk][q] = *(const float4*)(W1 + (size_t)(k0 + kk) * D_HID + j0 + q * 4);
        #pragma unroll
        for (int kk = 0; kk < 4; kk++) {
            #pragma unroll
            for (int mi = 0; mi < 4; mi++) {
                const float xm = ((const float*)&xv[mi])[kk];
                #pragma unroll
                for (int q = 0; q < 4; q++) {
                    acc[mi][q * 4 + 0] += xm * wv[kk][q].x;
                    acc[mi][q * 4 + 1] += xm * wv[kk][q].y;
                    acc[mi][q * 4 + 2] += xm * wv[kk][q].z;
                    acc[mi][q * 4 + 3] += xm * wv[kk][q].w;
                }
            }
        }
    }

    // ---- GEMM2 partials: p[mi][t] = sum_{jj in my 16 cols} relu(h)*W2[j][t]
    // W2 (16 KB) read straight from global: L1/L2-resident broadcast.
    float p[4][16];
    #pragma unroll
    for (int mi = 0; mi < 4; mi++)
        #pragma unroll
        for (int t = 0; t < 16; t++)
            p[mi][t] = 0.f;

    #pragma unroll
    for (int jj = 0; jj < 16; jj++) {
        float4 w2v[4];
        #pragma unroll
        for (int q = 0; q < 4; q++)
            w2v[q] = *(const float4*)(W2 + (size_t)(j0 + jj) * K_CL + q * 4);
        #pragma unroll
        for (int mi = 0; mi < 4; mi++) {
            const float h = fmaxf(acc[mi][jj], 0.f);
            #pragma unroll
            for (int q = 0; q < 4; q++) {
                p[mi][q * 4 + 0] += h * w2v[q].x;
                p[mi][q * 4 + 1] += h * w2v[q].y;
                p[mi][q * 4 + 2] += h * w2v[q].z;
                p[mi][q * 4 + 3] += h * w2v[q].w;
            }
        }
    }

    // ---- butterfly-reduce over the 16 tc lanes (lane bits 0..3, in-wave) ----
    #pragma unroll
    for (int mi = 0; mi < 4; mi++)
        #pragma unroll
        for (int t = 0; t < 16; t++) {
            float v = p[mi][t];
            v += __shfl_xor(v, 1);
            v += __shfl_xor(v, 2);
            v += __shfl_xor(v, 4);
            v += __shfl_xor(v, 8);
            p[mi][t] = v;   // every lane now holds the full logit row
        }

    float b2v[16];
    #pragma unroll
    for (int t = 0; t < 16; t++) b2v[t] = b2[t];

    // ---- softmax per node, in-lane; lane tc writes element tc (coalesced) ----
    #pragma unroll
    for (int mi = 0; mi < 4; mi++) {
        float logit[16];
        float mx = -1e30f;
        #pragma unroll
        for (int t = 0; t < 16; t++) {
            logit[t] = p[mi][t] + b2v[t];
            mx = fmaxf(mx, logit[t]);
        }
        float sum = 0.f;
        #pragma unroll
        for (int t = 0; t < 16; t++) {
            logit[t] = __expf(logit[t] - mx);
            sum += logit[t];
        }
        const float inv = 1.0f / sum;
        float mine = 0.f;
        #pragma unroll
        for (int t = 0; t < 16; t++) mine = (t == tc) ? logit[t] : mine;
        const int m = m0 + tr * 4 + mi;
        if (m < N_NODES) C[(size_t)m * K_CL + tc] = mine * inv;
    }
}

// ---------------------------------------------------------------------------
// Edge reduction: sum over edges of dot(C[src], C[dst])
// ---------------------------------------------------------------------------
__global__ __launch_bounds__(256) void edge_kernel(
    const int* __restrict__ ei, const float* __restrict__ C,
    float* __restrict__ acc)
{
    __shared__ float red[4];
    const int tid = threadIdx.x;
    float s = 0.f;
    for (long long e = (long long)blockIdx.x * 256 + tid; e < N_EDGES;
         e += (long long)gridDim.x * 256) {
        const int u = ei[e];
        const int v = ei[N_EDGES + e];
        const float4* cu = (const float4*)(C + (size_t)u * K_CL);
        const float4* cv = (const float4*)(C + (size_t)v * K_CL);
        #pragma unroll
        for (int q = 0; q < 4; q++) {
            const float4 a = cu[q], b = cv[q];
            s += a.x * b.x + a.y * b.y + a.z * b.z + a.w * b.w;
        }
    }
    #pragma unroll
    for (int off = 32; off > 0; off >>= 1) s += __shfl_down(s, off);
    if ((tid & 63) == 0) red[tid >> 6] = s;
    __syncthreads();
    if (tid == 0) atomicAdd(acc, red[0] + red[1] + red[2] + red[3]);
}

__global__ void finalize_kernel(const float* __restrict__ acc,
                                float* __restrict__ out)
{
    out[(size_t)N_NODES * K_CL] = -acc[0] / (float)N_EDGES;
}

// ---------------------------------------------------------------------------
extern "C" void kernel_launch(void* const* d_in, const int* in_sizes, int n_in,
                              void* d_out, int out_size, void* d_ws, size_t ws_size,
                              hipStream_t stream) {
    const float* x  = (const float*)d_in[0];
    const int*   ei = (const int*)  d_in[1];
    const float* W1 = (const float*)d_in[2];
    const float* b1 = (const float*)d_in[3];
    const float* W2 = (const float*)d_in[4];
    const float* b2 = (const float*)d_in[5];
    float* out = (float*)d_out;
    float* acc = (float*)d_ws;

    hipMemsetAsync(d_ws, 0, sizeof(float), stream);   // acc poisoned 0xAA each call

    const int n_tiles = (N_NODES + 63) / 64;          // 1563
    mlp_kernel<<<n_tiles, 256, 0, stream>>>(x, W1, b1, W2, b2, out);
    edge_kernel<<<1024, 256, 0, stream>>>(ei, out, acc);
    finalize_kernel<<<1, 1, 0, stream>>>(acc, out);
}

// Round 2
// 260.481 us; speedup vs baseline: 1.5920x; 1.5920x over previous
//
#include <hip/hip_runtime.h>

#define N_NODES 100000
#define D_INF   128
#define D_HID   256
#define K_CL    16
#define N_EDGES 3200000

typedef __attribute__((ext_vector_type(8))) __bf16  bf16x8;
typedef __attribute__((ext_vector_type(8))) unsigned short u16x8;
typedef __attribute__((ext_vector_type(4))) float   f32x4;

__device__ __forceinline__ unsigned short f2bf(float f) {
    unsigned int u = __builtin_bit_cast(unsigned int, f);
    u += 0x7fffu + ((u >> 16) & 1u);          // RNE
    return (unsigned short)(u >> 16);
}

// ---------------------------------------------------------------------------
// Prep: W1 [128][256] f32 -> W1T [256][128] bf16 ; W2 [256][16] f32 -> W2T
// [16][256] bf16 ; zero the edge accumulator.
// ---------------------------------------------------------------------------
__global__ void prep_kernel(const float* __restrict__ W1,
                            const float* __restrict__ W2,
                            unsigned short* __restrict__ w1t,
                            unsigned short* __restrict__ w2t,
                            float* __restrict__ acc)
{
    const int i = blockIdx.x * 256 + threadIdx.x;
    if (i == 0) *acc = 0.f;
    if (i < D_INF * D_HID) {                    // read coalesced, scatter write
        const int k = i >> 8, n = i & 255;
        w1t[n * D_INF + k] = f2bf(W1[i]);
    }
    if (i < D_HID * K_CL) {
        const int n = i >> 4, t = i & 15;
        w2t[t * D_HID + n] = f2bf(W2[i]);
    }
}

// ---------------------------------------------------------------------------
// Fused MLP, MFMA 16x16x32 bf16. One wave = one 16-node tile; block = 4 waves.
// No __syncthreads: each wave round-trips its h tile through a private LDS
// region (in-wave DS ordering + compiler lgkmcnt).
//   GEMM1: A = x tile (fp32->bf16 in regs), B = W1T rows, 16 n-tiles x 4 k.
//   h (relu+b1) -> LDS [16][258] bf16 (stride 258: ~2-way banks on reads).
//   GEMM2: A = h from LDS, B = W2T rows (L1-resident), 8 k-chunks.
//   Softmax across the 16 lanes of each quad-group via shfl_xor.
// ---------------------------------------------------------------------------
#define HSTR 258

__global__ __launch_bounds__(256, 3) void mlp_kernel(
    const float* __restrict__ x, const unsigned short* __restrict__ W1T,
    const float* __restrict__ b1, const unsigned short* __restrict__ W2T,
    const float* __restrict__ b2, float* __restrict__ C)
{
    __shared__ unsigned short hbuf[4][16 * HSTR];   // 33 KB

    const int tid  = threadIdx.x;
    const int wv   = tid >> 6;
    const int lane = tid & 63;
    const int c    = lane & 15;     // col within 16-tile
    const int q    = lane >> 4;     // quad (k-chunk slice / m-row group)

    const int mtile = blockIdx.x * 4 + wv;
    if (mtile * 16 >= N_NODES) return;
    const int m0 = mtile * 16;

    unsigned short* hl = &hbuf[wv][0];

    f32x4 acc[16];
    #pragma unroll
    for (int nt = 0; nt < 16; nt++) acc[nt] = (f32x4){0.f, 0.f, 0.f, 0.f};

    // ---- GEMM1 ----
    #pragma unroll
    for (int kc = 0; kc < 4; kc++) {
        // A-frag: x[m0+c][kc*32 + q*8 .. +7], fp32 -> bf16
        const float* xp = x + (size_t)(m0 + c) * D_INF + kc * 32 + q * 8;
        const float4 xa = *(const float4*)xp;
        const float4 xb = *(const float4*)(xp + 4);
        u16x8 af;
        af[0] = f2bf(xa.x); af[1] = f2bf(xa.y); af[2] = f2bf(xa.z); af[3] = f2bf(xa.w);
        af[4] = f2bf(xb.x); af[5] = f2bf(xb.y); af[6] = f2bf(xb.z); af[7] = f2bf(xb.w);
        const bf16x8 afrag = __builtin_bit_cast(bf16x8, af);

        const unsigned short* wb = W1T + (size_t)c * D_INF + kc * 32 + q * 8;
        #pragma unroll
        for (int nt = 0; nt < 16; nt++) {
            const bf16x8 bfrag = *(const bf16x8*)(wb + nt * 16 * D_INF);
            acc[nt] = __builtin_amdgcn_mfma_f32_16x16x32_bf16(afrag, bfrag, acc[nt], 0, 0, 0);
        }
    }

    // ---- epilogue 1: h = relu(acc + b1) -> LDS [m'][n], m' = 4q+r, n = nt*16+c
    #pragma unroll
    for (int nt = 0; nt < 16; nt++) {
        const float bv = b1[nt * 16 + c];
        #pragma unroll
        for (int r = 0; r < 4; r++) {
            const float hv = fmaxf(acc[nt][r] + bv, 0.f);
            hl[(4 * q + r) * HSTR + nt * 16 + c] = f2bf(hv);
        }
    }

    // ---- GEMM2: logits[16 m][16 t] ----
    f32x4 acc2 = (f32x4){0.f, 0.f, 0.f, 0.f};
    #pragma unroll
    for (int kc2 = 0; kc2 < 8; kc2++) {
        const bf16x8 a2 = *(const bf16x8*)(hl + c * HSTR + kc2 * 32 + q * 8);
        const bf16x8 b2f = *(const bf16x8*)(W2T + c * D_HID + kc2 * 32 + q * 8);
        acc2 = __builtin_amdgcn_mfma_f32_16x16x32_bf16(a2, b2f, acc2, 0, 0, 0);
    }

    // ---- softmax per row m' = 4q+r across the 16 lanes of quad-group q ----
    const float bt = b2[c];
    #pragma unroll
    for (int r = 0; r < 4; r++) {
        const float l = acc2[r] + bt;
        float mx = l;
        mx = fmaxf(mx, __shfl_xor(mx, 1));
        mx = fmaxf(mx, __shfl_xor(mx, 2));
        mx = fmaxf(mx, __shfl_xor(mx, 4));
        mx = fmaxf(mx, __shfl_xor(mx, 8));
        const float e = __expf(l - mx);
        float sm = e;
        sm += __shfl_xor(sm, 1);
        sm += __shfl_xor(sm, 2);
        sm += __shfl_xor(sm, 4);
        sm += __shfl_xor(sm, 8);
        C[(size_t)(m0 + 4 * q + r) * K_CL + c] = e / sm;
    }
}

// ---------------------------------------------------------------------------
// Edge reduction: 16 lanes per edge; lane t accumulates C[u][t]*C[v][t].
// One gather instruction serves 4 edges' full 64 B rows.
// ---------------------------------------------------------------------------
__global__ __launch_bounds__(256) void edge_kernel(
    const int* __restrict__ ei, const float* __restrict__ C,
    float* __restrict__ acc)
{
    __shared__ float red[4];
    const int tid  = threadIdx.x;
    const int lane = tid & 63;
    const int wv   = tid >> 6;
    const int t    = lane & 15;
    const int g    = lane >> 4;

    const long long wid    = (long long)blockIdx.x * 4 + wv;
    const long long stride = (long long)gridDim.x * 16;   // 4 waves * 4 groups

    float s = 0.f;
    for (long long e = wid * 4 + g; e < N_EDGES; e += stride) {
        const int u = ei[e];
        const int v = ei[N_EDGES + e];
        s += C[(size_t)u * K_CL + t] * C[(size_t)v * K_CL + t];
    }
    s += __shfl_xor(s, 1);
    s += __shfl_xor(s, 2);
    s += __shfl_xor(s, 4);
    s += __shfl_xor(s, 8);
    s += __shfl_xor(s, 16);
    s += __shfl_xor(s, 32);
    if (lane == 0) red[wv] = s;
    __syncthreads();
    if (tid == 0) atomicAdd(acc, red[0] + red[1] + red[2] + red[3]);
}

__global__ void finalize_kernel(const float* __restrict__ acc,
                                float* __restrict__ out)
{
    out[(size_t)N_NODES * K_CL] = -acc[0] / (float)N_EDGES;
}

// ---------------------------------------------------------------------------
extern "C" void kernel_launch(void* const* d_in, const int* in_sizes, int n_in,
                              void* d_out, int out_size, void* d_ws, size_t ws_size,
                              hipStream_t stream) {
    const float* x  = (const float*)d_in[0];
    const int*   ei = (const int*)  d_in[1];
    const float* W1 = (const float*)d_in[2];
    const float* b1 = (const float*)d_in[3];
    const float* W2 = (const float*)d_in[4];
    const float* b2 = (const float*)d_in[5];
    float* out = (float*)d_out;

    // ws layout: W1T bf16 [256*128] @0, W2T bf16 [16*256] @65536 B, acc @73728 B
    unsigned short* w1t = (unsigned short*)d_ws;
    unsigned short* w2t = (unsigned short*)((char*)d_ws + 65536);
    float*          acc = (float*)((char*)d_ws + 73728);

    prep_kernel<<<128, 256, 0, stream>>>(W1, W2, w1t, w2t, acc);

    const int n_blocks = (N_NODES / 16 + 3) / 4;   // 6250 m-tiles / 4 waves
    mlp_kernel<<<n_blocks, 256, 0, stream>>>(x, w1t, b1, w2t, b2, out);

    edge_kernel<<<2048, 256, 0, stream>>>(ei, out, acc);
    finalize_kernel<<<1, 1, 0, stream>>>(acc, out);
}

// Round 3
// 253.831 us; speedup vs baseline: 1.6337x; 1.0262x over previous
//
#include <hip/hip_runtime.h>

#define N_NODES 100000
#define D_INF   128
#define D_HID   256
#define K_CL    16
#define N_EDGES 3200000
#define N_TILES (N_NODES / 16)      // 6250, exact

typedef __attribute__((ext_vector_type(8))) __bf16  bf16x8;
typedef __attribute__((ext_vector_type(8))) unsigned short u16x8;
typedef __attribute__((ext_vector_type(4))) float   f32x4;

__device__ __forceinline__ unsigned short f2bf(float f) {
    unsigned int u = __builtin_bit_cast(unsigned int, f);
    u += 0x7fffu + ((u >> 16) & 1u);          // RNE
    return (unsigned short)(u >> 16);
}
__device__ __forceinline__ float bflo(unsigned int p) {   // low bf16 -> f32
    return __builtin_bit_cast(float, p << 16);
}
__device__ __forceinline__ float bfhi(unsigned int p) {   // high bf16 -> f32
    return __builtin_bit_cast(float, p & 0xffff0000u);
}

// ---------------------------------------------------------------------------
// Prep: W1 [128][256] f32 -> W1T [256][128] bf16 ; W2 [256][16] f32 -> W2T
// [16][256] bf16 ; zero the edge accumulator.
// ---------------------------------------------------------------------------
__global__ void prep_kernel(const float* __restrict__ W1,
                            const float* __restrict__ W2,
                            unsigned short* __restrict__ w1t,
                            unsigned short* __restrict__ w2t,
                            float* __restrict__ acc)
{
    const int i = blockIdx.x * 256 + threadIdx.x;
    if (i == 0) *acc = 0.f;
    if (i < D_INF * D_HID) {
        const int k = i >> 8, n = i & 255;
        w1t[n * D_INF + k] = f2bf(W1[i]);
    }
    if (i < D_HID * K_CL) {
        const int n = i >> 4, t = i & 15;
        w2t[t * D_HID + n] = f2bf(W2[i]);
    }
}

// ---------------------------------------------------------------------------
// Fused MLP, MFMA 16x16x32 bf16. Block = 4 waves; wave = one 16-node tile,
// grid-stride over the 6250 tiles. W1T staged in LDS once per block
// (padded stride 136 bf16 -> 2-way bank aliasing only = free). W2T frags,
// b1, b2 live in registers across the whole loop. GEMM2 transposes h
// through a double-buffered 16x32 per-wave LDS chunk (in-wave DS ordering,
// no __syncthreads in the loop).
// ---------------------------------------------------------------------------
#define W1S 136      // LDS row stride (bf16) for W1T
#define CHS 40       // LDS row stride (bf16) for h chunk

__global__ __launch_bounds__(256, 2) void mlp_kernel(
    const float* __restrict__ x, const unsigned short* __restrict__ W1T,
    const float* __restrict__ b1, const unsigned short* __restrict__ W2T,
    const float* __restrict__ b2, float* __restrict__ C,
    unsigned short* __restrict__ Cb)
{
    __shared__ unsigned short w1s[256 * W1S];          // 69,632 B
    __shared__ unsigned short chbuf[4][2][16 * CHS];   // 10,240 B  (total 79,872)

    const int tid  = threadIdx.x;
    const int wv   = tid >> 6;
    const int lane = tid & 63;
    const int c    = lane & 15;
    const int q    = lane >> 4;

    // ---- stage W1T into LDS (coalesced uint4 reads, b128 LDS writes) ----
    #pragma unroll
    for (int it = 0; it < 16; ++it) {
        const int idx = it * 256 + tid;        // 4096 uint4 chunks
        const int row = idx >> 4, ch = idx & 15;
        const uint4 v = ((const uint4*)W1T)[idx];
        *(uint4*)&w1s[row * W1S + ch * 8] = v;
    }

    // ---- loop-invariant registers: W2T fragments, biases ----
    bf16x8 w2f[8];
    #pragma unroll
    for (int kc2 = 0; kc2 < 8; ++kc2)
        w2f[kc2] = *(const bf16x8*)(W2T + (size_t)c * D_HID + kc2 * 32 + q * 8);
    float b1v[16];
    #pragma unroll
    for (int nt = 0; nt < 16; ++nt) b1v[nt] = b1[nt * 16 + c];
    const float b2v = b2[c];
    __syncthreads();

    unsigned short* const ch0 = &chbuf[wv][0][0];
    unsigned short* const ch1 = &chbuf[wv][1][0];

    const int wid     = blockIdx.x * 4 + wv;
    const int wstride = gridDim.x * 4;

    for (int tile = wid; tile < N_TILES; tile += wstride) {
        const int m0 = tile * 16;

        // ---- A fragments: x rows m0+c, fp32 -> bf16 in regs ----
        const float* xrow = x + (size_t)(m0 + c) * D_INF + q * 8;
        bf16x8 afr[4];
        #pragma unroll
        for (int kc = 0; kc < 4; ++kc) {
            const float4 xa = *(const float4*)(xrow + kc * 32);
            const float4 xb = *(const float4*)(xrow + kc * 32 + 4);
            u16x8 af;
            af[0] = f2bf(xa.x); af[1] = f2bf(xa.y); af[2] = f2bf(xa.z); af[3] = f2bf(xa.w);
            af[4] = f2bf(xb.x); af[5] = f2bf(xb.y); af[6] = f2bf(xb.z); af[7] = f2bf(xb.w);
            afr[kc] = __builtin_bit_cast(bf16x8, af);
        }

        // ---- GEMM1: 64 MFMA, B-frags from LDS ----
        f32x4 acc[16];
        #pragma unroll
        for (int nt = 0; nt < 16; ++nt) acc[nt] = (f32x4){0.f, 0.f, 0.f, 0.f};
        #pragma unroll
        for (int kc = 0; kc < 4; ++kc)
            #pragma unroll
            for (int nt = 0; nt < 16; ++nt) {
                const bf16x8 bf = *(const bf16x8*)&w1s[(nt * 16 + c) * W1S + kc * 32 + q * 8];
                acc[nt] = __builtin_amdgcn_mfma_f32_16x16x32_bf16(afr[kc], bf, acc[nt], 0, 0, 0);
            }

        // ---- GEMM2: chunked transpose through LDS, 8 MFMA ----
        f32x4 acc2 = (f32x4){0.f, 0.f, 0.f, 0.f};
        #pragma unroll
        for (int kc2 = 0; kc2 < 8; ++kc2) {
            unsigned short* const cb = (kc2 & 1) ? ch1 : ch0;
            #pragma unroll
            for (int half = 0; half < 2; ++half) {
                const int nt = kc2 * 2 + half;
                const float bv = b1v[nt];
                #pragma unroll
                for (int r = 0; r < 4; ++r)
                    cb[(4 * q + r) * CHS + half * 16 + c] =
                        f2bf(fmaxf(acc[nt][r] + bv, 0.f));
            }
            const bf16x8 a2 = *(const bf16x8*)&cb[c * CHS + q * 8];
            acc2 = __builtin_amdgcn_mfma_f32_16x16x32_bf16(a2, w2f[kc2], acc2, 0, 0, 0);
        }

        // ---- softmax per row m = 4q+r across 16 c-lanes; dual store ----
        #pragma unroll
        for (int r = 0; r < 4; ++r) {
            const float l = acc2[r] + b2v;
            float mx = l;
            mx = fmaxf(mx, __shfl_xor(mx, 1));
            mx = fmaxf(mx, __shfl_xor(mx, 2));
            mx = fmaxf(mx, __shfl_xor(mx, 4));
            mx = fmaxf(mx, __shfl_xor(mx, 8));
            const float e = __expf(l - mx);
            float sm = e;
            sm += __shfl_xor(sm, 1);
            sm += __shfl_xor(sm, 2);
            sm += __shfl_xor(sm, 4);
            sm += __shfl_xor(sm, 8);
            const float p = e / sm;
            const size_t o = (size_t)(m0 + 4 * q + r) * K_CL + c;
            C[o]  = p;
            Cb[o] = f2bf(p);
        }
    }
}

// ---------------------------------------------------------------------------
// Edge reduction on the bf16 C copy (3.2 MB -> per-XCD-L2-resident).
// 8 lanes per edge, each lane handles 2 bf16 via a dword gather; two
// independent edges per lane per iteration to break the idx->gather chain.
// ---------------------------------------------------------------------------
__global__ __launch_bounds__(256) void edge_kernel(
    const int* __restrict__ ei, const unsigned short* __restrict__ Cb,
    float* __restrict__ acc)
{
    __shared__ float red[4];
    const int tid  = threadIdx.x;
    const int lane = tid & 63;
    const int wv   = tid >> 6;
    const int t    = lane & 7;      // bf16-pair index within row
    const int g    = lane >> 3;     // edge group (8 per wave)

    const long long wid    = (long long)blockIdx.x * 4 + wv;
    const long long stride = (long long)gridDim.x * 64;   // 4 waves * 16 edges

    float s = 0.f;
    // N_EDGES % 16 == 0, so e0 and e0+8 are always both valid
    for (long long e0 = wid * 16 + g; e0 < N_EDGES; e0 += stride) {
        const long long e1 = e0 + 8;
        const int u0 = ei[e0],           v0 = ei[N_EDGES + e0];
        const int u1 = ei[e1],           v1 = ei[N_EDGES + e1];
        const unsigned int a0 = *(const unsigned int*)(Cb + (size_t)u0 * K_CL + t * 2);
        const unsigned int b0 = *(const unsigned int*)(Cb + (size_t)v0 * K_CL + t * 2);
        const unsigned int a1 = *(const unsigned int*)(Cb + (size_t)u1 * K_CL + t * 2);
        const unsigned int b1 = *(const unsigned int*)(Cb + (size_t)v1 * K_CL + t * 2);
        s = fmaf(bflo(a0), bflo(b0), s);
        s = fmaf(bfhi(a0), bfhi(b0), s);
        s = fmaf(bflo(a1), bflo(b1), s);
        s = fmaf(bfhi(a1), bfhi(b1), s);
    }
    s += __shfl_xor(s, 1);
    s += __shfl_xor(s, 2);
    s += __shfl_xor(s, 4);
    s += __shfl_xor(s, 8);
    s += __shfl_xor(s, 16);
    s += __shfl_xor(s, 32);
    if (lane == 0) red[wv] = s;
    __syncthreads();
    if (tid == 0) atomicAdd(acc, red[0] + red[1] + red[2] + red[3]);
}

__global__ void finalize_kernel(const float* __restrict__ acc,
                                float* __restrict__ out)
{
    out[(size_t)N_NODES * K_CL] = -acc[0] / (float)N_EDGES;
}

// ---------------------------------------------------------------------------
extern "C" void kernel_launch(void* const* d_in, const int* in_sizes, int n_in,
                              void* d_out, int out_size, void* d_ws, size_t ws_size,
                              hipStream_t stream) {
    const float* x  = (const float*)d_in[0];
    const int*   ei = (const int*)  d_in[1];
    const float* W1 = (const float*)d_in[2];
    const float* b1 = (const float*)d_in[3];
    const float* W2 = (const float*)d_in[4];
    const float* b2 = (const float*)d_in[5];
    float* out = (float*)d_out;

    // ws: W1T bf16 @0 (64 KB), W2T bf16 @65536 (8 KB), acc @73728,
    //     Cb bf16 [100000*16] @73760 (3.2 MB)
    unsigned short* w1t = (unsigned short*)d_ws;
    unsigned short* w2t = (unsigned short*)((char*)d_ws + 65536);
    float*          acc = (float*)((char*)d_ws + 73728);
    unsigned short* Cb  = (unsigned short*)((char*)d_ws + 73760);

    prep_kernel<<<128, 256, 0, stream>>>(W1, W2, w1t, w2t, acc);
    mlp_kernel<<<512, 256, 0, stream>>>(x, w1t, b1, w2t, b2, out, Cb);
    edge_kernel<<<1024, 256, 0, stream>>>(ei, Cb, acc);
    finalize_kernel<<<1, 1, 0, stream>>>(acc, out);
}

// Round 4
// 161.132 us; speedup vs baseline: 2.5736x; 1.5753x over previous
//
#include <hip/hip_runtime.h>

#define N_NODES 100000
#define D_INF   128
#define D_HID   256
#define K_CL    16
#define N_EDGES 3200000
#define N_TILES (N_NODES / 16)      // 6250, exact

typedef __attribute__((ext_vector_type(8))) __bf16  bf16x8;
typedef __attribute__((ext_vector_type(8))) unsigned short u16x8;
typedef __attribute__((ext_vector_type(4))) float   f32x4;

__device__ __forceinline__ unsigned short f2bf(float f) {
    unsigned int u = __builtin_bit_cast(unsigned int, f);
    u += 0x7fffu + ((u >> 16) & 1u);          // RNE
    return (unsigned short)(u >> 16);
}
__device__ __forceinline__ float bflo(unsigned int p) {   // low bf16 -> f32
    return __builtin_bit_cast(float, p << 16);
}
__device__ __forceinline__ float bfhi(unsigned int p) {   // high bf16 -> f32
    return __builtin_bit_cast(float, p & 0xffff0000u);
}

// ---------------------------------------------------------------------------
// Prep: W1 [128][256] f32 -> W1T [256][128] bf16 ; W2 [256][16] f32 -> W2T
// [16][256] bf16 ; zero accumulator. Writes coalesced (reads are small/L2).
// ---------------------------------------------------------------------------
__global__ void prep_kernel(const float* __restrict__ W1,
                            const float* __restrict__ W2,
                            unsigned short* __restrict__ w1t,
                            unsigned short* __restrict__ w2t,
                            float* __restrict__ acc)
{
    const int i = blockIdx.x * 256 + threadIdx.x;
    if (i == 0) *acc = 0.f;
    if (i < D_INF * D_HID) {                  // w1t[n][k] = W1[k][n]
        const int n = i >> 7, k = i & 127;
        w1t[i] = f2bf(W1[k * D_HID + n]);
    }
    if (i < D_HID * K_CL) {                   // w2t[t][n] = W2[n][t]
        const int t = i >> 8, n = i & 255;
        w2t[i] = f2bf(W2[n * K_CL + t]);
    }
}

// ---------------------------------------------------------------------------
// Fused MLP, MFMA 16x16x32 bf16. Block = 4 waves; wave = one 16-node tile,
// grid-stride over 6250 tiles. W1T staged in LDS once per block (stride 136
// bf16: lane bank-starts 4c%32, b128 spans don't collide -> conflict-free).
// Register-pressure-shaped K-loop: only ONE hidden 16-col accumulator live
// at a time (8 VGPRs), h chunk round-trips through per-wave LDS (no
// __syncthreads in the loop), GEMM2 MFMA consumes it immediately.
// ---------------------------------------------------------------------------
#define W1S 136      // LDS row stride (bf16) for W1T
#define CHS 40       // LDS row stride (bf16) for h chunk

__global__ __launch_bounds__(256, 2) void mlp_kernel(
    const float* __restrict__ x, const unsigned short* __restrict__ W1T,
    const float* __restrict__ b1, const unsigned short* __restrict__ W2T,
    const float* __restrict__ b2, float* __restrict__ C,
    unsigned short* __restrict__ Cb)
{
    __shared__ unsigned short w1s[256 * W1S];          // 69,632 B
    __shared__ unsigned short chbuf[4][2][16 * CHS];   // 10,240 B
    __shared__ float b1s[D_HID];                       //  1,024 B -> 80,896 total

    const int tid  = threadIdx.x;
    const int wv   = tid >> 6;
    const int lane = tid & 63;
    const int c    = lane & 15;
    const int q    = lane >> 4;

    // ---- stage W1T into LDS (coalesced uint4 reads, b128 LDS writes) ----
    #pragma unroll
    for (int it = 0; it < 16; ++it) {
        const int idx = it * 256 + tid;        // 4096 uint4 chunks
        const int row = idx >> 4, ch = idx & 15;
        const uint4 v = ((const uint4*)W1T)[idx];
        *(uint4*)&w1s[row * W1S + ch * 8] = v;
    }
    if (tid < D_HID) b1s[tid] = b1[tid];

    // ---- loop-invariant registers: W2T fragments (32 VGPRs), b2 ----
    bf16x8 w2f[8];
    #pragma unroll
    for (int kc2 = 0; kc2 < 8; ++kc2)
        w2f[kc2] = *(const bf16x8*)(W2T + (size_t)c * D_HID + kc2 * 32 + q * 8);
    const float b2v = b2[c];
    __syncthreads();

    unsigned short* const chA = &chbuf[wv][0][0];
    unsigned short* const chB = &chbuf[wv][1][0];

    const int wid     = blockIdx.x * 4 + wv;
    const int wstride = gridDim.x * 4;

    for (int tile = wid; tile < N_TILES; tile += wstride) {
        const int m0 = tile * 16;

        // ---- A fragments: x row m0+c, fp32 -> bf16 in regs (16 VGPRs) ----
        const float* xrow = x + (size_t)(m0 + c) * D_INF + q * 8;
        bf16x8 afr[4];
        #pragma unroll
        for (int kc = 0; kc < 4; ++kc) {
            const float4 xa = *(const float4*)(xrow + kc * 32);
            const float4 xb = *(const float4*)(xrow + kc * 32 + 4);
            u16x8 af;
            af[0] = f2bf(xa.x); af[1] = f2bf(xa.y); af[2] = f2bf(xa.z); af[3] = f2bf(xa.w);
            af[4] = f2bf(xb.x); af[5] = f2bf(xb.y); af[6] = f2bf(xb.z); af[7] = f2bf(xb.w);
            afr[kc] = __builtin_bit_cast(bf16x8, af);
        }

        // ---- fused GEMM1 -> h chunk -> GEMM2, one nt-pair at a time ----
        f32x4 acc2 = (f32x4){0.f, 0.f, 0.f, 0.f};
        #pragma unroll
        for (int kc2 = 0; kc2 < 8; ++kc2) {
            unsigned short* const cb = (kc2 & 1) ? chB : chA;
            #pragma unroll
            for (int half = 0; half < 2; ++half) {
                const int nt = kc2 * 2 + half;
                f32x4 a1 = (f32x4){0.f, 0.f, 0.f, 0.f};
                #pragma unroll
                for (int kc = 0; kc < 4; ++kc) {
                    const bf16x8 bf =
                        *(const bf16x8*)&w1s[(nt * 16 + c) * W1S + kc * 32 + q * 8];
                    a1 = __builtin_amdgcn_mfma_f32_16x16x32_bf16(afr[kc], bf, a1, 0, 0, 0);
                }
                const float bv = b1s[nt * 16 + c];
                #pragma unroll
                for (int r = 0; r < 4; ++r)
                    cb[(4 * q + r) * CHS + half * 16 + c] =
                        f2bf(fmaxf(a1[r] + bv, 0.f));
            }
            const bf16x8 a2 = *(const bf16x8*)&cb[c * CHS + q * 8];
            acc2 = __builtin_amdgcn_mfma_f32_16x16x32_bf16(a2, w2f[kc2], acc2, 0, 0, 0);
        }

        // ---- softmax per row m = 4q+r across 16 c-lanes; dual store ----
        #pragma unroll
        for (int r = 0; r < 4; ++r) {
            const float l = acc2[r] + b2v;
            float mx = l;
            mx = fmaxf(mx, __shfl_xor(mx, 1));
            mx = fmaxf(mx, __shfl_xor(mx, 2));
            mx = fmaxf(mx, __shfl_xor(mx, 4));
            mx = fmaxf(mx, __shfl_xor(mx, 8));
            const float e = __expf(l - mx);
            float sm = e;
            sm += __shfl_xor(sm, 1);
            sm += __shfl_xor(sm, 2);
            sm += __shfl_xor(sm, 4);
            sm += __shfl_xor(sm, 8);
            const float p = e / sm;
            const size_t o = (size_t)(m0 + 4 * q + r) * K_CL + c;
            C[o]  = p;
            Cb[o] = f2bf(p);
        }
    }
}

// ---------------------------------------------------------------------------
// Edge reduction on the bf16 C copy (3.2 MB, per-XCD-L2-resident).
// 4 lanes per edge (uint2 = 4 bf16 each), 2 independent edges per lane per
// iteration: 8 VMEM instructions per 32 edges (0.25 instr/edge).
// ---------------------------------------------------------------------------
__global__ __launch_bounds__(256) void edge_kernel(
    const int* __restrict__ ei, const unsigned short* __restrict__ Cb,
    float* __restrict__ acc)
{
    __shared__ float red[4];
    const int tid  = threadIdx.x;
    const int lane = tid & 63;
    const int wv   = tid >> 6;
    const int t    = lane & 3;      // uint2 index within 32 B row
    const int g    = lane >> 2;     // edge group (16 per wave)

    const long long wid    = (long long)blockIdx.x * 4 + wv;
    const long long stride = (long long)gridDim.x * 4 * 32;

    float s = 0.f;
    // N_EDGES % 32 == 0: e0 and e0+16 always both valid
    for (long long base = wid * 32; base < N_EDGES; base += stride) {
        const long long e0 = base + g, e1 = e0 + 16;
        const int u0 = ei[e0], v0 = ei[N_EDGES + e0];
        const int u1 = ei[e1], v1 = ei[N_EDGES + e1];
        const uint2 a0 = *(const uint2*)(Cb + (size_t)u0 * K_CL + t * 4);
        const uint2 b0 = *(const uint2*)(Cb + (size_t)v0 * K_CL + t * 4);
        const uint2 a1 = *(const uint2*)(Cb + (size_t)u1 * K_CL + t * 4);
        const uint2 b1 = *(const uint2*)(Cb + (size_t)v1 * K_CL + t * 4);
        s = fmaf(bflo(a0.x), bflo(b0.x), s);
        s = fmaf(bfhi(a0.x), bfhi(b0.x), s);
        s = fmaf(bflo(a0.y), bflo(b0.y), s);
        s = fmaf(bfhi(a0.y), bfhi(b0.y), s);
        s = fmaf(bflo(a1.x), bflo(b1.x), s);
        s = fmaf(bfhi(a1.x), bfhi(b1.x), s);
        s = fmaf(bflo(a1.y), bflo(b1.y), s);
        s = fmaf(bfhi(a1.y), bfhi(b1.y), s);
    }
    s += __shfl_xor(s, 1);
    s += __shfl_xor(s, 2);
    s += __shfl_xor(s, 4);
    s += __shfl_xor(s, 8);
    s += __shfl_xor(s, 16);
    s += __shfl_xor(s, 32);
    if (lane == 0) red[wv] = s;
    __syncthreads();
    if (tid == 0) atomicAdd(acc, red[0] + red[1] + red[2] + red[3]);
}

__global__ void finalize_kernel(const float* __restrict__ acc,
                                float* __restrict__ out)
{
    out[(size_t)N_NODES * K_CL] = -acc[0] / (float)N_EDGES;
}

// ---------------------------------------------------------------------------
extern "C" void kernel_launch(void* const* d_in, const int* in_sizes, int n_in,
                              void* d_out, int out_size, void* d_ws, size_t ws_size,
                              hipStream_t stream) {
    const float* x  = (const float*)d_in[0];
    const int*   ei = (const int*)  d_in[1];
    const float* W1 = (const float*)d_in[2];
    const float* b1 = (const float*)d_in[3];
    const float* W2 = (const float*)d_in[4];
    const float* b2 = (const float*)d_in[5];
    float* out = (float*)d_out;

    // ws: W1T bf16 @0 (64 KB), W2T bf16 @65536 (8 KB), acc @73728,
    //     Cb bf16 [100000*16] @73760 (3.2 MB)
    unsigned short* w1t = (unsigned short*)d_ws;
    unsigned short* w2t = (unsigned short*)((char*)d_ws + 65536);
    float*          acc = (float*)((char*)d_ws + 73728);
    unsigned short* Cb  = (unsigned short*)((char*)d_ws + 73760);

    prep_kernel<<<128, 256, 0, stream>>>(W1, W2, w1t, w2t, acc);
    mlp_kernel<<<512, 256, 0, stream>>>(x, w1t, b1, w2t, b2, out, Cb);
    edge_kernel<<<1024, 256, 0, stream>>>(ei, Cb, acc);
    finalize_kernel<<<1, 1, 0, stream>>>(acc, out);
}